// Round 1
// baseline (1771.852 us; speedup 1.0000x reference)
//
#include <hip/hip_runtime.h>
#include <math.h>

// Problem constants
constexpr int NN = 50000;      // nodes
constexpr int NE = 800000;     // edges
constexpr int HD = 128;        // hidden
constexpr int GD = 64;         // global feat dim
constexpr int NG = 10;         // groups
constexpr float LAM = 0.01f;
constexpr float EPSV = 1e-5f;

__device__ __forceinline__ float softplus_f(float x) {
    // stable log1p(exp(x))
    return fmaxf(x, 0.f) + log1pf(expf(-fabsf(x)));
}

// -------------------- scatter: messages = segment_sum(edge_features, row) -----
__global__ __launch_bounds__(256) void scatter_kernel(
    const float* __restrict__ ef, const int* __restrict__ rows,
    float* __restrict__ msg)
{
    int gid = blockIdx.x * 256 + threadIdx.x;
    int e = gid >> 5;          // 32 threads per edge
    int c = (gid & 31) * 4;
    if (e >= NE) return;
    int r = rows[e];
    float4 v = *reinterpret_cast<const float4*>(ef + (size_t)e * HD + c);
    float* dst = msg + (size_t)r * HD + c;
    atomicAdd(dst + 0, v.x);
    atomicAdd(dst + 1, v.y);
    atomicAdd(dst + 2, v.z);
    atomicAdd(dst + 3, v.w);
}

// -------------------- generic f32 GEMM: C = act(A[N,K] @ W[K,128] + b) --------
// BM=64 rows/block, 256 threads, each thread: 8 rows x 4 cols
template<int K, bool CONCAT, bool SP, bool WRITE2>
__global__ __launch_bounds__(256) void gemm_kernel(
    const float* __restrict__ A, const float* __restrict__ A2,
    const float* __restrict__ GF,
    const float* __restrict__ W, const float* __restrict__ bias,
    float* __restrict__ C, float* __restrict__ C2)
{
    __shared__ float As[64 * 32];
    __shared__ float Ws[32 * 128];
    const int tid = threadIdx.x;
    const int m0 = blockIdx.x * 64;
    const int tc = tid & 31;    // col group
    const int tr = tid >> 5;    // row group (8 rows each)

    float acc[8][4];
    #pragma unroll
    for (int i = 0; i < 8; ++i)
        #pragma unroll
        for (int j = 0; j < 4; ++j) acc[i][j] = 0.f;

    for (int k0 = 0; k0 < K; k0 += 32) {
        // stage A tile (64x32): 512 float4, 2 per thread, consecutive lanes
        #pragma unroll
        for (int i = 0; i < 2; ++i) {
            int f = tid + i * 256;
            int row = f >> 3;
            int col = (f & 7) * 4;
            int grow = m0 + row;
            int gk = k0 + col;
            float4 v = make_float4(0.f, 0.f, 0.f, 0.f);
            if (grow < NN) {
                if (!CONCAT) {
                    v = *reinterpret_cast<const float4*>(A + (size_t)grow * K + gk);
                } else {
                    if (gk < 128)
                        v = *reinterpret_cast<const float4*>(A + (size_t)grow * 128 + gk);
                    else if (gk < 256)
                        v = *reinterpret_cast<const float4*>(A2 + (size_t)grow * 128 + (gk - 128));
                    else
                        v = *reinterpret_cast<const float4*>(GF + (gk - 256));
                }
            }
            *reinterpret_cast<float4*>(As + row * 32 + col) = v;
        }
        // stage W tile (32x128): 1024 float4, 4 per thread
        #pragma unroll
        for (int i = 0; i < 4; ++i) {
            int f = tid + i * 256;
            int row = f >> 5;
            int col = (f & 31) * 4;
            *reinterpret_cast<float4*>(Ws + row * 128 + col) =
                *reinterpret_cast<const float4*>(W + (size_t)(k0 + row) * 128 + col);
        }
        __syncthreads();
        #pragma unroll
        for (int kk = 0; kk < 32; ++kk) {
            float wv[4];
            #pragma unroll
            for (int j = 0; j < 4; ++j) wv[j] = Ws[kk * 128 + tc + 32 * j];
            #pragma unroll
            for (int i = 0; i < 8; ++i) {
                float av = As[(tr * 8 + i) * 32 + kk];
                #pragma unroll
                for (int j = 0; j < 4; ++j) acc[i][j] += av * wv[j];
            }
        }
        __syncthreads();
    }
    #pragma unroll
    for (int i = 0; i < 8; ++i) {
        int row = m0 + tr * 8 + i;
        if (row >= NN) break;
        #pragma unroll
        for (int j = 0; j < 4; ++j) {
            int col = tc + 32 * j;
            float v = acc[i][j] + bias[col];
            if (SP) v = softplus_f(v);
            C[(size_t)row * 128 + col] = v;
            if (WRITE2) C2[(size_t)row * 128 + col] = v;
        }
    }
}

// -------------------- s = softmax(h @ linW + linb) over G=10 ------------------
// 4 threads (quad) per node, 64 nodes per block
__global__ __launch_bounds__(256) void softmax_kernel(
    const float* __restrict__ h, const float* __restrict__ linW,
    const float* __restrict__ linb, float* __restrict__ s)
{
    __shared__ float hs[64 * 132];
    __shared__ float lw[10 * 132];
    const int tid = threadIdx.x;
    const int nbase = blockIdx.x * 64;
    #pragma unroll
    for (int i = 0; i < 8; ++i) {
        int f = tid + i * 256;         // 2048 float4
        int row = f >> 5;
        int col = (f & 31) * 4;
        int n = nbase + row;
        float4 v = make_float4(0.f, 0.f, 0.f, 0.f);
        if (n < NN) v = *reinterpret_cast<const float4*>(h + (size_t)n * 128 + col);
        *reinterpret_cast<float4*>(hs + row * 132 + col) = v;
    }
    for (int idx = tid; idx < 1280; idx += 256) {
        int k = idx / 10, g = idx % 10;
        lw[g * 132 + k] = linW[idx];
    }
    __syncthreads();
    const int node = tid >> 2;
    const int part = tid & 3;
    float acc[10];
    #pragma unroll
    for (int g = 0; g < 10; ++g) acc[g] = 0.f;
    #pragma unroll
    for (int kk = 0; kk < 32; ++kk) {
        float hv = hs[node * 132 + part + 4 * kk];
        #pragma unroll
        for (int g = 0; g < 10; ++g) acc[g] += hv * lw[g * 132 + part + 4 * kk];
    }
    #pragma unroll
    for (int g = 0; g < 10; ++g) {
        acc[g] += __shfl_xor(acc[g], 1);
        acc[g] += __shfl_xor(acc[g], 2);
        acc[g] += linb[g];
    }
    int gn = nbase + node;
    if (gn < NN) {
        float m = acc[0];
        #pragma unroll
        for (int g = 1; g < 10; ++g) m = fmaxf(m, acc[g]);
        float sum = 0.f;
        float ex[10];
        #pragma unroll
        for (int g = 0; g < 10; ++g) { ex[g] = expf(acc[g] - m); sum += ex[g]; }
        float inv = 1.f / sum;
        #pragma unroll
        for (int q = 0; q < 3; ++q) {
            int gg = part + 4 * q;
            if (gg < 10) s[(size_t)gn * 10 + gg] = ex[gg] * inv;
        }
    }
}

// -------------------- batch stats: sum1 = sum_n s*h, sum2 = sum_n (s*h)^2 -----
__global__ __launch_bounds__(256) void stats_kernel(
    const float* __restrict__ h, const float* __restrict__ s,
    float* __restrict__ sum1, float* __restrict__ sum2)
{
    __shared__ float hs[64 * 128];
    __shared__ float ss[64 * 10];
    const int tid = threadIdx.x;
    const int c = tid & 127;
    const int g0 = (tid >> 7) * 5;
    float a1[5], a2[5];
    #pragma unroll
    for (int q = 0; q < 5; ++q) { a1[q] = 0.f; a2[q] = 0.f; }

    const int nchunks = (NN + 63) / 64;   // 782
    for (int chunk = blockIdx.x; chunk < nchunks; chunk += gridDim.x) {
        int nbase = chunk * 64;
        #pragma unroll
        for (int i = 0; i < 8; ++i) {
            int f = tid + i * 256;
            int row = f >> 5, col = (f & 31) * 4;
            int n = nbase + row;
            float4 v = make_float4(0.f, 0.f, 0.f, 0.f);
            if (n < NN) v = *reinterpret_cast<const float4*>(h + (size_t)n * 128 + col);
            *reinterpret_cast<float4*>(hs + row * 128 + col) = v;
        }
        for (int idx = tid; idx < 640; idx += 256) {
            int row = idx / 10, g = idx % 10;
            int n = nbase + row;
            ss[idx] = (n < NN) ? s[(size_t)n * 10 + g] : 0.f;
        }
        __syncthreads();
        int nmax = min(64, NN - nbase);
        for (int n = 0; n < nmax; ++n) {
            float hv = hs[n * 128 + c];
            #pragma unroll
            for (int q = 0; q < 5; ++q) {
                float p = ss[n * 10 + g0 + q] * hv;
                a1[q] += p;
                a2[q] += p * p;
            }
        }
        __syncthreads();
    }
    #pragma unroll
    for (int q = 0; q < 5; ++q) {
        atomicAdd(&sum1[(g0 + q) * 128 + c], a1[q]);
        atomicAdd(&sum2[(g0 + q) * 128 + c], a2[q]);
    }
}

// -------------------- finalize: w = rsqrt(var+eps)*gamma, K[c] = sum beta-mu*w
__global__ void finalize_kernel(
    const float* __restrict__ sum1, const float* __restrict__ sum2,
    const float* __restrict__ gamma, const float* __restrict__ beta,
    float* __restrict__ w, float* __restrict__ kvec)
{
    int c = threadIdx.x;   // 128 threads
    float kacc = 0.f;
    const float invn = 1.f / (float)NN;
    for (int g = 0; g < NG; ++g) {
        int idx = g * 128 + c;
        float mu = sum1[idx] * invn;
        float var = sum2[idx] * invn - mu * mu;
        float inv = rsqrtf(var + EPSV);
        float wg = inv * gamma[idx];
        w[idx] = wg;
        kacc += beta[idx] - mu * wg;
    }
    kvec[c] = kacc;
}

// -------------------- apply: dst = out + h + LAM*(h*A + K) [+ initial] --------
template<bool LAST>
__global__ __launch_bounds__(256) void apply_kernel(
    const float* __restrict__ out, const float* __restrict__ h,
    const float* __restrict__ s, const float* __restrict__ w,
    const float* __restrict__ kvec, const float* __restrict__ initial,
    float* __restrict__ dst)
{
    __shared__ float ws_[1280];
    __shared__ float ks_[128];
    const int tid = threadIdx.x;
    for (int i = tid; i < 1280; i += 256) ws_[i] = w[i];
    if (tid < 128) ks_[tid] = kvec[tid];
    __syncthreads();
    const int c = tid & 127;
    const int half = tid >> 7;
    const int nbase = blockIdx.x * 64;
    for (int nn = 0; nn < 32; ++nn) {
        int n = nbase + nn * 2 + half;
        if (n >= NN) continue;
        float A = 0.f;
        #pragma unroll
        for (int g = 0; g < 10; ++g) A += s[(size_t)n * 10 + g] * ws_[g * 128 + c];
        float hv = h[(size_t)n * 128 + c];
        float ov = out[(size_t)n * 128 + c];
        float res = ov + hv + LAM * (hv * A + ks_[c]);
        if (LAST) res += initial[(size_t)n * 128 + c];
        dst[(size_t)n * 128 + c] = res;
    }
}

// ------------------------------------------------------------------------------
extern "C" void kernel_launch(void* const* d_in, const int* in_sizes, int n_in,
                              void* d_out, int out_size, void* d_ws, size_t ws_size,
                              hipStream_t stream)
{
    const float* x    = (const float*)d_in[0];
    const int*   eidx = (const int*)  d_in[1];
    const float* ef   = (const float*)d_in[2];
    const float* gf   = (const float*)d_in[3];
    const float* Wc   = (const float*)d_in[4];
    const float* bc   = (const float*)d_in[5];

    float* outb = (float*)d_out;              // running "out" buffer (N*128)
    float* ws   = (float*)d_ws;
    float* msg     = ws;                       // N*128 (messages, reused as t)
    float* initial = ws + (size_t)NN * HD;     // N*128
    float* hbuf    = ws + (size_t)2 * NN * HD; // N*128
    float* sbuf    = ws + (size_t)3 * NN * HD; // N*10
    float* sum1    = sbuf + (size_t)NN * NG;   // 1280
    float* sum2    = sum1 + 1280;              // 1280
    float* wbuf    = sum1 + 2560;              // 1280
    float* kvec    = sum1 + 3840;              // 128

    // messages = segment_sum(edge_features, row)
    hipMemsetAsync(msg, 0, sizeof(float) * (size_t)NN * HD, stream);
    scatter_kernel<<<(NE * 32) / 256, 256, 0, stream>>>(ef, eidx, msg);

    // out = initial = softplus([x | msg | g] @ Wc + bc)
    const int gblocks = (NN + 63) / 64;  // 782
    gemm_kernel<320, true, true, true><<<gblocks, 256, 0, stream>>>(
        x, msg, gf, Wc, bc, outb, initial);

    for (int b = 0; b < 2; ++b) {
        const float* W1    = (const float*)d_in[6 + 8 * b];
        const float* b1    = (const float*)d_in[7 + 8 * b];
        const float* W2    = (const float*)d_in[8 + 8 * b];
        const float* b2    = (const float*)d_in[9 + 8 * b];
        const float* linW  = (const float*)d_in[10 + 8 * b];
        const float* linb  = (const float*)d_in[11 + 8 * b];
        const float* gamma = (const float*)d_in[12 + 8 * b];
        const float* beta  = (const float*)d_in[13 + 8 * b];

        // t = softplus(out @ W1 + b1)   (t reuses msg buffer)
        gemm_kernel<128, false, true, false><<<gblocks, 256, 0, stream>>>(
            outb, nullptr, nullptr, W1, b1, msg, nullptr);
        // h = t @ W2 + b2
        gemm_kernel<128, false, false, false><<<gblocks, 256, 0, stream>>>(
            msg, nullptr, nullptr, W2, b2, hbuf, nullptr);
        // s = softmax(h @ linW + linb)
        softmax_kernel<<<gblocks, 256, 0, stream>>>(hbuf, linW, linb, sbuf);
        // batch stats
        hipMemsetAsync(sum1, 0, sizeof(float) * 2560, stream);
        stats_kernel<<<256, 256, 0, stream>>>(hbuf, sbuf, sum1, sum2);
        finalize_kernel<<<1, 128, 0, stream>>>(sum1, sum2, gamma, beta, wbuf, kvec);
        // out = out + h + LAM*(h*A + K)  (+ initial on last block -> d_out)
        if (b == 0)
            apply_kernel<false><<<gblocks, 256, 0, stream>>>(
                outb, hbuf, sbuf, wbuf, kvec, nullptr, outb);
        else
            apply_kernel<true><<<gblocks, 256, 0, stream>>>(
                outb, hbuf, sbuf, wbuf, kvec, initial, outb);
    }
}

// Round 2
// 744.016 us; speedup vs baseline: 2.3815x; 2.3815x over previous
//
#include <hip/hip_runtime.h>
#include <math.h>

// Problem constants
constexpr int NN = 50000;      // nodes
constexpr int NE = 800000;     // edges
constexpr int HD = 128;        // hidden
constexpr int GD = 64;         // global feat dim
constexpr int NG = 10;         // groups
constexpr float LAM = 0.01f;
constexpr float EPSV = 1e-5f;

__device__ __forceinline__ float softplus_f(float x) {
    return fmaxf(x, 0.f) + log1pf(expf(-fabsf(x)));
}

// -------------------- CSR build: histogram of edge destinations ---------------
__global__ __launch_bounds__(256) void hist_kernel(
    const int* __restrict__ rows, int* __restrict__ cnt)
{
    int e = blockIdx.x * 256 + threadIdx.x;
    if (e < NE) atomicAdd(&cnt[rows[e]], 1);
}

// -------------------- CSR build: exclusive scan (single block) ----------------
// cnt_cur: in = counts, out = running cursor (= exclusive offsets)
__global__ __launch_bounds__(1024) void scan_kernel(
    int* __restrict__ cnt_cur, int* __restrict__ off)
{
    __shared__ int part[1024];
    const int t = threadIdx.x;
    constexpr int CH = (NN + 1023) / 1024;   // 49
    int base = t * CH;
    int sum = 0;
    for (int j = 0; j < CH; ++j) {
        int i = base + j;
        if (i < NN) sum += cnt_cur[i];
    }
    part[t] = sum;
    __syncthreads();
    // Hillis-Steele inclusive scan
    for (int d = 1; d < 1024; d <<= 1) {
        int v = (t >= d) ? part[t - d] : 0;
        __syncthreads();
        part[t] += v;
        __syncthreads();
    }
    int run = part[t] - sum;   // exclusive prefix of this chunk
    for (int j = 0; j < CH; ++j) {
        int i = base + j;
        if (i < NN) {
            int c = cnt_cur[i];
            off[i] = run;
            cnt_cur[i] = run;   // cursor for fill
            run += c;
        }
    }
    if (t == 1023) off[NN] = NE;
}

// -------------------- CSR build: bucket fill ----------------------------------
__global__ __launch_bounds__(256) void fill_kernel(
    const int* __restrict__ rows, int* __restrict__ cur, int* __restrict__ eid)
{
    int e = blockIdx.x * 256 + threadIdx.x;
    if (e < NE) {
        int slot = atomicAdd(&cur[rows[e]], 1);
        eid[slot] = e;
    }
}

// -------------------- gather: msg[n] = sum of ef rows of n's edges ------------
// one 64-lane wave per node, float2 per lane = 512B per edge row
__global__ __launch_bounds__(256) void gather_kernel(
    const float* __restrict__ ef, const int* __restrict__ off,
    const int* __restrict__ eid, float* __restrict__ msg)
{
    int node = blockIdx.x * 4 + (threadIdx.x >> 6);
    int lane = threadIdx.x & 63;
    if (node >= NN) return;
    int b = off[node], e_end = off[node + 1];
    float2 acc0 = make_float2(0.f, 0.f), acc1 = make_float2(0.f, 0.f);
    int i = b;
    for (; i + 1 < e_end; i += 2) {
        int e0 = eid[i], e1 = eid[i + 1];
        float2 v0 = *reinterpret_cast<const float2*>(ef + (size_t)e0 * HD + 2 * lane);
        float2 v1 = *reinterpret_cast<const float2*>(ef + (size_t)e1 * HD + 2 * lane);
        acc0.x += v0.x; acc0.y += v0.y;
        acc1.x += v1.x; acc1.y += v1.y;
    }
    if (i < e_end) {
        int e0 = eid[i];
        float2 v0 = *reinterpret_cast<const float2*>(ef + (size_t)e0 * HD + 2 * lane);
        acc0.x += v0.x; acc0.y += v0.y;
    }
    float2 r = make_float2(acc0.x + acc1.x, acc0.y + acc1.y);
    *reinterpret_cast<float2*>(msg + (size_t)node * HD + 2 * lane) = r;
}

// -------------------- generic f32 GEMM: C = act(A[N,K] @ W[K,128] + b) --------
// BM=64 rows/block, 256 threads, each thread: 8 rows x 4 cols
template<int K, bool CONCAT, bool SP, bool WRITE2>
__global__ __launch_bounds__(256) void gemm_kernel(
    const float* __restrict__ A, const float* __restrict__ A2,
    const float* __restrict__ GF,
    const float* __restrict__ W, const float* __restrict__ bias,
    float* __restrict__ C, float* __restrict__ C2)
{
    __shared__ float As[64 * 32];
    __shared__ float Ws[32 * 128];
    const int tid = threadIdx.x;
    const int m0 = blockIdx.x * 64;
    const int tc = tid & 31;    // col group
    const int tr = tid >> 5;    // row group (8 rows each)

    float acc[8][4];
    #pragma unroll
    for (int i = 0; i < 8; ++i)
        #pragma unroll
        for (int j = 0; j < 4; ++j) acc[i][j] = 0.f;

    for (int k0 = 0; k0 < K; k0 += 32) {
        #pragma unroll
        for (int i = 0; i < 2; ++i) {
            int f = tid + i * 256;
            int row = f >> 3;
            int col = (f & 7) * 4;
            int grow = m0 + row;
            int gk = k0 + col;
            float4 v = make_float4(0.f, 0.f, 0.f, 0.f);
            if (grow < NN) {
                if (!CONCAT) {
                    v = *reinterpret_cast<const float4*>(A + (size_t)grow * K + gk);
                } else {
                    if (gk < 128)
                        v = *reinterpret_cast<const float4*>(A + (size_t)grow * 128 + gk);
                    else if (gk < 256)
                        v = *reinterpret_cast<const float4*>(A2 + (size_t)grow * 128 + (gk - 128));
                    else
                        v = *reinterpret_cast<const float4*>(GF + (gk - 256));
                }
            }
            *reinterpret_cast<float4*>(As + row * 32 + col) = v;
        }
        #pragma unroll
        for (int i = 0; i < 4; ++i) {
            int f = tid + i * 256;
            int row = f >> 5;
            int col = (f & 31) * 4;
            *reinterpret_cast<float4*>(Ws + row * 128 + col) =
                *reinterpret_cast<const float4*>(W + (size_t)(k0 + row) * 128 + col);
        }
        __syncthreads();
        #pragma unroll
        for (int kk = 0; kk < 32; ++kk) {
            float wv[4];
            #pragma unroll
            for (int j = 0; j < 4; ++j) wv[j] = Ws[kk * 128 + tc + 32 * j];
            #pragma unroll
            for (int i = 0; i < 8; ++i) {
                float av = As[(tr * 8 + i) * 32 + kk];
                #pragma unroll
                for (int j = 0; j < 4; ++j) acc[i][j] += av * wv[j];
            }
        }
        __syncthreads();
    }
    #pragma unroll
    for (int i = 0; i < 8; ++i) {
        int row = m0 + tr * 8 + i;
        if (row >= NN) break;
        #pragma unroll
        for (int j = 0; j < 4; ++j) {
            int col = tc + 32 * j;
            float v = acc[i][j] + bias[col];
            if (SP) v = softplus_f(v);
            C[(size_t)row * 128 + col] = v;
            if (WRITE2) C2[(size_t)row * 128 + col] = v;
        }
    }
}

// -------------------- s = softmax(h @ linW + linb) over G=10 ------------------
__global__ __launch_bounds__(256) void softmax_kernel(
    const float* __restrict__ h, const float* __restrict__ linW,
    const float* __restrict__ linb, float* __restrict__ s)
{
    __shared__ float hs[64 * 132];
    __shared__ float lw[10 * 132];
    const int tid = threadIdx.x;
    const int nbase = blockIdx.x * 64;
    #pragma unroll
    for (int i = 0; i < 8; ++i) {
        int f = tid + i * 256;
        int row = f >> 5;
        int col = (f & 31) * 4;
        int n = nbase + row;
        float4 v = make_float4(0.f, 0.f, 0.f, 0.f);
        if (n < NN) v = *reinterpret_cast<const float4*>(h + (size_t)n * 128 + col);
        *reinterpret_cast<float4*>(hs + row * 132 + col) = v;
    }
    for (int idx = tid; idx < 1280; idx += 256) {
        int k = idx / 10, g = idx % 10;
        lw[g * 132 + k] = linW[idx];
    }
    __syncthreads();
    const int node = tid >> 2;
    const int part = tid & 3;
    float acc[10];
    #pragma unroll
    for (int g = 0; g < 10; ++g) acc[g] = 0.f;
    #pragma unroll
    for (int kk = 0; kk < 32; ++kk) {
        float hv = hs[node * 132 + part + 4 * kk];
        #pragma unroll
        for (int g = 0; g < 10; ++g) acc[g] += hv * lw[g * 132 + part + 4 * kk];
    }
    #pragma unroll
    for (int g = 0; g < 10; ++g) {
        acc[g] += __shfl_xor(acc[g], 1);
        acc[g] += __shfl_xor(acc[g], 2);
        acc[g] += linb[g];
    }
    int gn = nbase + node;
    if (gn < NN) {
        float m = acc[0];
        #pragma unroll
        for (int g = 1; g < 10; ++g) m = fmaxf(m, acc[g]);
        float sum = 0.f;
        float ex[10];
        #pragma unroll
        for (int g = 0; g < 10; ++g) { ex[g] = expf(acc[g] - m); sum += ex[g]; }
        float inv = 1.f / sum;
        #pragma unroll
        for (int q = 0; q < 3; ++q) {
            int gg = part + 4 * q;
            if (gg < 10) s[(size_t)gn * 10 + gg] = ex[gg] * inv;
        }
    }
}

// -------------------- batch stats: sum1 = sum_n s*h, sum2 = sum_n (s*h)^2 -----
__global__ __launch_bounds__(256) void stats_kernel(
    const float* __restrict__ h, const float* __restrict__ s,
    float* __restrict__ sum1, float* __restrict__ sum2)
{
    __shared__ float hs[64 * 128];
    __shared__ float ss[64 * 10];
    const int tid = threadIdx.x;
    const int c = tid & 127;
    const int g0 = (tid >> 7) * 5;
    float a1[5], a2[5];
    #pragma unroll
    for (int q = 0; q < 5; ++q) { a1[q] = 0.f; a2[q] = 0.f; }

    const int nchunks = (NN + 63) / 64;   // 782
    for (int chunk = blockIdx.x; chunk < nchunks; chunk += gridDim.x) {
        int nbase = chunk * 64;
        #pragma unroll
        for (int i = 0; i < 8; ++i) {
            int f = tid + i * 256;
            int row = f >> 5, col = (f & 31) * 4;
            int n = nbase + row;
            float4 v = make_float4(0.f, 0.f, 0.f, 0.f);
            if (n < NN) v = *reinterpret_cast<const float4*>(h + (size_t)n * 128 + col);
            *reinterpret_cast<float4*>(hs + row * 128 + col) = v;
        }
        for (int idx = tid; idx < 640; idx += 256) {
            int row = idx / 10, g = idx % 10;
            int n = nbase + row;
            ss[idx] = (n < NN) ? s[(size_t)n * 10 + g] : 0.f;
        }
        __syncthreads();
        int nmax = min(64, NN - nbase);
        for (int n = 0; n < nmax; ++n) {
            float hv = hs[n * 128 + c];
            #pragma unroll
            for (int q = 0; q < 5; ++q) {
                float p = ss[n * 10 + g0 + q] * hv;
                a1[q] += p;
                a2[q] += p * p;
            }
        }
        __syncthreads();
    }
    #pragma unroll
    for (int q = 0; q < 5; ++q) {
        atomicAdd(&sum1[(g0 + q) * 128 + c], a1[q]);
        atomicAdd(&sum2[(g0 + q) * 128 + c], a2[q]);
    }
}

// -------------------- finalize: w = rsqrt(var+eps)*gamma, K[c] = sum beta-mu*w
__global__ void finalize_kernel(
    const float* __restrict__ sum1, const float* __restrict__ sum2,
    const float* __restrict__ gamma, const float* __restrict__ beta,
    float* __restrict__ w, float* __restrict__ kvec)
{
    int c = threadIdx.x;   // 128 threads
    float kacc = 0.f;
    const float invn = 1.f / (float)NN;
    for (int g = 0; g < NG; ++g) {
        int idx = g * 128 + c;
        float mu = sum1[idx] * invn;
        float var = sum2[idx] * invn - mu * mu;
        float inv = rsqrtf(var + EPSV);
        float wg = inv * gamma[idx];
        w[idx] = wg;
        kacc += beta[idx] - mu * wg;
    }
    kvec[c] = kacc;
}

// -------------------- apply: dst = out + h + LAM*(h*A + K) [+ initial] --------
template<bool LAST>
__global__ __launch_bounds__(256) void apply_kernel(
    const float* __restrict__ out, const float* __restrict__ h,
    const float* __restrict__ s, const float* __restrict__ w,
    const float* __restrict__ kvec, const float* __restrict__ initial,
    float* __restrict__ dst)
{
    __shared__ float ws_[1280];
    __shared__ float ks_[128];
    const int tid = threadIdx.x;
    for (int i = tid; i < 1280; i += 256) ws_[i] = w[i];
    if (tid < 128) ks_[tid] = kvec[tid];
    __syncthreads();
    const int c = tid & 127;
    const int half = tid >> 7;
    const int nbase = blockIdx.x * 64;
    for (int nn = 0; nn < 32; ++nn) {
        int n = nbase + nn * 2 + half;
        if (n >= NN) continue;
        float A = 0.f;
        #pragma unroll
        for (int g = 0; g < 10; ++g) A += s[(size_t)n * 10 + g] * ws_[g * 128 + c];
        float hv = h[(size_t)n * 128 + c];
        float ov = out[(size_t)n * 128 + c];
        float res = ov + hv + LAM * (hv * A + ks_[c]);
        if (LAST) res += initial[(size_t)n * 128 + c];
        dst[(size_t)n * 128 + c] = res;
    }
}

// ------------------------------------------------------------------------------
extern "C" void kernel_launch(void* const* d_in, const int* in_sizes, int n_in,
                              void* d_out, int out_size, void* d_ws, size_t ws_size,
                              hipStream_t stream)
{
    const float* x    = (const float*)d_in[0];
    const int*   eidx = (const int*)  d_in[1];
    const float* ef   = (const float*)d_in[2];
    const float* gf   = (const float*)d_in[3];
    const float* Wc   = (const float*)d_in[4];
    const float* bc   = (const float*)d_in[5];

    float* outb = (float*)d_out;              // running "out" buffer (N*128)
    float* ws   = (float*)d_ws;
    float* msg     = ws;                       // N*128 (messages, reused as t)
    float* initial = ws + (size_t)NN * HD;     // N*128
    float* hbuf    = ws + (size_t)2 * NN * HD; // N*128
    float* sbuf    = ws + (size_t)3 * NN * HD; // N*10
    float* sum1    = sbuf + (size_t)NN * NG;   // 1280
    float* sum2    = sum1 + 1280;              // 1280
    float* wbuf    = sum1 + 2560;              // 1280
    float* kvec    = sum1 + 3840;              // 128

    // CSR scratch aliased into buffers not yet written:
    //  - cnt/cursor + off live in `initial` (written later by combine GEMM)
    //  - eid lives in `hbuf` (written later in the block loop)
    int* cnt = (int*)initial;          // NN ints (becomes cursor after scan)
    int* off = ((int*)initial) + NN;   // NN+1 ints
    int* eid = (int*)hbuf;             // NE ints

    // ---- messages = segment_sum(edge_features, row), atomic-free gather ----
    hipMemsetAsync(cnt, 0, sizeof(int) * (size_t)NN, stream);
    hist_kernel<<<(NE + 255) / 256, 256, 0, stream>>>(eidx, cnt);
    scan_kernel<<<1, 1024, 0, stream>>>(cnt, off);
    fill_kernel<<<(NE + 255) / 256, 256, 0, stream>>>(eidx, cnt, eid);
    gather_kernel<<<(NN + 3) / 4, 256, 0, stream>>>(ef, off, eid, msg);

    // out = initial = softplus([x | msg | g] @ Wc + bc)
    const int gblocks = (NN + 63) / 64;  // 782
    gemm_kernel<320, true, true, true><<<gblocks, 256, 0, stream>>>(
        x, msg, gf, Wc, bc, outb, initial);

    for (int b = 0; b < 2; ++b) {
        const float* W1    = (const float*)d_in[6 + 8 * b];
        const float* b1    = (const float*)d_in[7 + 8 * b];
        const float* W2    = (const float*)d_in[8 + 8 * b];
        const float* b2    = (const float*)d_in[9 + 8 * b];
        const float* linW  = (const float*)d_in[10 + 8 * b];
        const float* linb  = (const float*)d_in[11 + 8 * b];
        const float* gamma = (const float*)d_in[12 + 8 * b];
        const float* beta  = (const float*)d_in[13 + 8 * b];

        // t = softplus(out @ W1 + b1)   (t reuses msg buffer)
        gemm_kernel<128, false, true, false><<<gblocks, 256, 0, stream>>>(
            outb, nullptr, nullptr, W1, b1, msg, nullptr);
        // h = t @ W2 + b2
        gemm_kernel<128, false, false, false><<<gblocks, 256, 0, stream>>>(
            msg, nullptr, nullptr, W2, b2, hbuf, nullptr);
        // s = softmax(h @ linW + linb)
        softmax_kernel<<<gblocks, 256, 0, stream>>>(hbuf, linW, linb, sbuf);
        // batch stats
        hipMemsetAsync(sum1, 0, sizeof(float) * 2560, stream);
        stats_kernel<<<256, 256, 0, stream>>>(hbuf, sbuf, sum1, sum2);
        finalize_kernel<<<1, 128, 0, stream>>>(sum1, sum2, gamma, beta, wbuf, kvec);
        // out = out + h + LAM*(h*A + K)  (+ initial on last block -> d_out)
        if (b == 0)
            apply_kernel<false><<<gblocks, 256, 0, stream>>>(
                outb, hbuf, sbuf, wbuf, kvec, nullptr, outb);
        else
            apply_kernel<true><<<gblocks, 256, 0, stream>>>(
                outb, hbuf, sbuf, wbuf, kvec, initial, outb);
    }
}

// Round 3
// 579.142 us; speedup vs baseline: 3.0594x; 1.2847x over previous
//
#include <hip/hip_runtime.h>
#include <math.h>

// Problem constants
constexpr int NN = 50000;      // nodes
constexpr int NE = 800000;     // edges
constexpr int HD = 128;        // hidden
constexpr int NG = 10;         // groups
constexpr float LAM = 0.01f;
constexpr float EPSV = 1e-5f;

typedef __attribute__((ext_vector_type(8))) short s8v;   // 8 bf16 (4 VGPRs)
typedef __attribute__((ext_vector_type(4))) float f4v;   // MFMA acc

__device__ __forceinline__ float softplus_f(float x) {
    return fmaxf(x, 0.f) + log1pf(expf(-fabsf(x)));
}
__device__ __forceinline__ unsigned short f2b(float f) {
    unsigned u = __float_as_uint(f);
    unsigned r = (u + 0x7FFFu + ((u >> 16) & 1u)) >> 16;
    return (unsigned short)r;
}

// -------------------- CSR build ------------------------------------------------
__global__ __launch_bounds__(256) void hist_kernel(
    const int* __restrict__ rows, int* __restrict__ cnt)
{
    int e = blockIdx.x * 256 + threadIdx.x;
    if (e < NE) atomicAdd(&cnt[rows[e]], 1);
}

__global__ __launch_bounds__(1024) void scan_kernel(
    int* __restrict__ cnt_cur, int* __restrict__ off)
{
    __shared__ int part[1024];
    const int t = threadIdx.x;
    constexpr int CH = (NN + 1023) / 1024;   // 49
    int base = t * CH;
    int sum = 0;
    for (int j = 0; j < CH; ++j) {
        int i = base + j;
        if (i < NN) sum += cnt_cur[i];
    }
    part[t] = sum;
    __syncthreads();
    for (int d = 1; d < 1024; d <<= 1) {
        int v = (t >= d) ? part[t - d] : 0;
        __syncthreads();
        part[t] += v;
        __syncthreads();
    }
    int run = part[t] - sum;
    for (int j = 0; j < CH; ++j) {
        int i = base + j;
        if (i < NN) {
            int c = cnt_cur[i];
            off[i] = run;
            cnt_cur[i] = run;
            run += c;
        }
    }
    if (t == 1023) off[NN] = NE;
}

__global__ __launch_bounds__(256) void fill_kernel(
    const int* __restrict__ rows, int* __restrict__ cur, int* __restrict__ eid)
{
    int e = blockIdx.x * 256 + threadIdx.x;
    if (e < NE) {
        int slot = atomicAdd(&cur[rows[e]], 1);
        eid[slot] = e;
    }
}

// -------------------- gather: msgbf[n] = bf16(sum of ef rows) ------------------
__global__ __launch_bounds__(256) void gather_kernel(
    const float* __restrict__ ef, const int* __restrict__ off,
    const int* __restrict__ eid, unsigned* __restrict__ msgbf)
{
    int node = blockIdx.x * 4 + (threadIdx.x >> 6);
    int lane = threadIdx.x & 63;
    if (node >= NN) return;
    int b = off[node], e_end = off[node + 1];
    float2 acc0 = make_float2(0.f, 0.f), acc1 = make_float2(0.f, 0.f);
    int i = b;
    for (; i + 1 < e_end; i += 2) {
        int e0 = eid[i], e1 = eid[i + 1];
        float2 v0 = *reinterpret_cast<const float2*>(ef + (size_t)e0 * HD + 2 * lane);
        float2 v1 = *reinterpret_cast<const float2*>(ef + (size_t)e1 * HD + 2 * lane);
        acc0.x += v0.x; acc0.y += v0.y;
        acc1.x += v1.x; acc1.y += v1.y;
    }
    if (i < e_end) {
        int e0 = eid[i];
        float2 v0 = *reinterpret_cast<const float2*>(ef + (size_t)e0 * HD + 2 * lane);
        acc0.x += v0.x; acc0.y += v0.y;
    }
    float rx = acc0.x + acc1.x, ry = acc0.y + acc1.y;
    unsigned pack = (unsigned)f2b(rx) | ((unsigned)f2b(ry) << 16);
    msgbf[(size_t)node * 64 + lane] = pack;
}

// -------------------- prep: weights -> bf16, transposed [n][k] -----------------
__global__ __launch_bounds__(256) void prep_kernel(
    const float* __restrict__ Wc,
    const float* __restrict__ W1a, const float* __restrict__ W2a,
    const float* __restrict__ W1b, const float* __restrict__ W2b,
    short* __restrict__ wct, short* __restrict__ wts)
{
    int i = blockIdx.x * 256 + threadIdx.x;
    if (i < 40960) {
        int n = i / 320, kk = i % 320;
        wct[i] = (short)f2b(Wc[kk * 128 + n]);
    } else if (i < 40960 + 4 * 16384) {
        int j = i - 40960;
        int mat = j >> 14;
        int idx = j & 16383;
        int n = idx >> 7, kk = idx & 127;
        const float* src = (mat == 0) ? W1a : (mat == 1) ? W2a : (mat == 2) ? W1b : W2b;
        wts[j] = (short)f2b(src[kk * 128 + n]);
    }
}

// -------------------- combine: out = initial = softplus([x|msg|g]@Wc + bc) ----
// MFMA, K=320 in 5 chunks of 64. 64 rows/block, 4 waves (16 rows each).
__global__ __launch_bounds__(256) void combine_mfma_kernel(
    const float* __restrict__ x, const short* __restrict__ msgbf,
    const float* __restrict__ gf, const short* __restrict__ wct,
    const float* __restrict__ bc,
    float* __restrict__ out, float* __restrict__ initial, short* __restrict__ outbf)
{
    __shared__ short As[64 * 72];
    __shared__ short Ws[128 * 72];
    __shared__ float bcs[128];
    const int tid = threadIdx.x;
    const int m0 = blockIdx.x * 64;
    if (tid < 128) bcs[tid] = bc[tid];
    const int lane = tid & 63;
    const int wv = tid >> 6;
    const int fr = lane & 15;      // frag row/col index
    const int fc = lane >> 4;      // k-chunk index

    f4v acc[8];
    #pragma unroll
    for (int ct = 0; ct < 8; ++ct) acc[ct] = (f4v){0.f, 0.f, 0.f, 0.f};

    const int arow = tid >> 2;
    const int aseg = (tid & 3) * 16;
    const int wcol = tid >> 1;
    const int wseg = (tid & 1) * 32;

    for (int c = 0; c < 5; ++c) {
        const int k0 = c * 64;
        // stage A chunk [64][64] -> As[64][72] bf16
        {
            short tmp[16];
            int grow = m0 + arow;
            if (grow >= NN) {
                #pragma unroll
                for (int j = 0; j < 16; ++j) tmp[j] = 0;
            } else if (c < 2) {
                const float* src = x + (size_t)grow * 128 + k0 + aseg;
                #pragma unroll
                for (int q = 0; q < 4; ++q) {
                    float4 v = *reinterpret_cast<const float4*>(src + 4 * q);
                    tmp[4*q+0] = (short)f2b(v.x); tmp[4*q+1] = (short)f2b(v.y);
                    tmp[4*q+2] = (short)f2b(v.z); tmp[4*q+3] = (short)f2b(v.w);
                }
            } else if (c < 4) {
                const short* src = msgbf + (size_t)grow * 128 + (k0 - 128) + aseg;
                *(s8v*)tmp = *(const s8v*)src;
                *(s8v*)(tmp + 8) = *(const s8v*)(src + 8);
            } else {
                const float* src = gf + aseg;
                #pragma unroll
                for (int q = 0; q < 4; ++q) {
                    float4 v = *reinterpret_cast<const float4*>(src + 4 * q);
                    tmp[4*q+0] = (short)f2b(v.x); tmp[4*q+1] = (short)f2b(v.y);
                    tmp[4*q+2] = (short)f2b(v.z); tmp[4*q+3] = (short)f2b(v.w);
                }
            }
            *(s8v*)&As[arow * 72 + aseg] = *(s8v*)tmp;
            *(s8v*)&As[arow * 72 + aseg + 8] = *(s8v*)(tmp + 8);
        }
        // stage W chunk: Wct[col][k0..k0+63] -> Ws[128][72]
        {
            const short* src = wct + (size_t)wcol * 320 + k0 + wseg;
            #pragma unroll
            for (int j = 0; j < 4; ++j)
                *(s8v*)&Ws[wcol * 72 + wseg + 8 * j] = *(const s8v*)(src + 8 * j);
        }
        __syncthreads();
        const short* ap = As + (wv * 16 + fr) * 72 + fc * 8;
        const short* bp = Ws + fr * 72 + fc * 8;
        #pragma unroll
        for (int ks = 0; ks < 2; ++ks) {
            s8v a = *(const s8v*)(ap + ks * 32);
            #pragma unroll
            for (int ct = 0; ct < 8; ++ct) {
                s8v b = *(const s8v*)(bp + ct * 16 * 72 + ks * 32);
                acc[ct] = __builtin_amdgcn_mfma_f32_16x16x32_bf16(a, b, acc[ct], 0, 0, 0);
            }
        }
        __syncthreads();
    }
    // epilogue: C/D layout col=lane&15, row=(lane>>4)*4+r
    const int rbase = m0 + wv * 16 + fc * 4;
    #pragma unroll
    for (int ct = 0; ct < 8; ++ct) {
        int col = ct * 16 + fr;
        float bv = bcs[col];
        #pragma unroll
        for (int r = 0; r < 4; ++r) {
            int row = rbase + r;
            if (row < NN) {
                float v = softplus_f(acc[ct][r] + bv);
                out[(size_t)row * 128 + col] = v;
                initial[(size_t)row * 128 + col] = v;
                outbf[(size_t)row * 128 + col] = (short)f2b(v);
            }
        }
    }
}

// -------------------- fused12: h = softplus(out@W1+b1)@W2 + b2 ----------------
__global__ __launch_bounds__(256) void fused12_kernel(
    const short* __restrict__ outbf, const short* __restrict__ w1t,
    const short* __restrict__ w2t, const float* __restrict__ b1,
    const float* __restrict__ b2, float* __restrict__ h)
{
    __shared__ short As[64 * 136];
    __shared__ short Ws[128 * 136];
    __shared__ short Ts[64 * 136];
    __shared__ float b1s[128], b2s[128];
    const int tid = threadIdx.x;
    const int m0 = blockIdx.x * 64;
    if (tid < 128) { b1s[tid] = b1[tid]; b2s[tid] = b2[tid]; }
    const int lane = tid & 63;
    const int wv = tid >> 6;
    const int fr = lane & 15;
    const int fc = lane >> 4;

    // stage A (out_bf16 tile)
    {
        int row = tid >> 2, seg = (tid & 3) * 32;
        int grow = m0 + row;
        s8v v[4];
        if (grow < NN) {
            const short* src = outbf + (size_t)grow * 128 + seg;
            #pragma unroll
            for (int j = 0; j < 4; ++j) v[j] = *(const s8v*)(src + 8 * j);
        } else {
            s8v z = {0,0,0,0,0,0,0,0};
            #pragma unroll
            for (int j = 0; j < 4; ++j) v[j] = z;
        }
        #pragma unroll
        for (int j = 0; j < 4; ++j) *(s8v*)&As[row * 136 + seg + 8 * j] = v[j];
    }
    // stage W1t
    {
        int col = tid >> 1, seg = (tid & 1) * 64;
        const short* src = w1t + (size_t)col * 128 + seg;
        #pragma unroll
        for (int j = 0; j < 8; ++j)
            *(s8v*)&Ws[col * 136 + seg + 8 * j] = *(const s8v*)(src + 8 * j);
    }
    __syncthreads();

    f4v acc[8];
    #pragma unroll
    for (int ct = 0; ct < 8; ++ct) acc[ct] = (f4v){0.f, 0.f, 0.f, 0.f};
    {
        const short* ap = As + (wv * 16 + fr) * 136 + fc * 8;
        const short* bp = Ws + fr * 136 + fc * 8;
        #pragma unroll
        for (int ks = 0; ks < 4; ++ks) {
            s8v a = *(const s8v*)(ap + ks * 32);
            #pragma unroll
            for (int ct = 0; ct < 8; ++ct) {
                s8v b = *(const s8v*)(bp + ct * 16 * 136 + ks * 32);
                acc[ct] = __builtin_amdgcn_mfma_f32_16x16x32_bf16(a, b, acc[ct], 0, 0, 0);
            }
        }
    }
    // t -> Ts (bf16, softplus applied)
    {
        int rb = wv * 16 + fc * 4;
        #pragma unroll
        for (int ct = 0; ct < 8; ++ct) {
            int col = ct * 16 + fr;
            float bv = b1s[col];
            #pragma unroll
            for (int r = 0; r < 4; ++r) {
                float v = softplus_f(acc[ct][r] + bv);
                Ts[(rb + r) * 136 + col] = (short)f2b(v);
            }
        }
    }
    __syncthreads();
    // stage W2t over Ws
    {
        int col = tid >> 1, seg = (tid & 1) * 64;
        const short* src = w2t + (size_t)col * 128 + seg;
        #pragma unroll
        for (int j = 0; j < 8; ++j)
            *(s8v*)&Ws[col * 136 + seg + 8 * j] = *(const s8v*)(src + 8 * j);
    }
    __syncthreads();

    #pragma unroll
    for (int ct = 0; ct < 8; ++ct) acc[ct] = (f4v){0.f, 0.f, 0.f, 0.f};
    {
        const short* ap = Ts + (wv * 16 + fr) * 136 + fc * 8;
        const short* bp = Ws + fr * 136 + fc * 8;
        #pragma unroll
        for (int ks = 0; ks < 4; ++ks) {
            s8v a = *(const s8v*)(ap + ks * 32);
            #pragma unroll
            for (int ct = 0; ct < 8; ++ct) {
                s8v b = *(const s8v*)(bp + ct * 16 * 136 + ks * 32);
                acc[ct] = __builtin_amdgcn_mfma_f32_16x16x32_bf16(a, b, acc[ct], 0, 0, 0);
            }
        }
    }
    {
        int rb = m0 + wv * 16 + fc * 4;
        #pragma unroll
        for (int ct = 0; ct < 8; ++ct) {
            int col = ct * 16 + fr;
            float bv = b2s[col];
            #pragma unroll
            for (int r = 0; r < 4; ++r) {
                int row = rb + r;
                if (row < NN) h[(size_t)row * 128 + col] = acc[ct][r] + bv;
            }
        }
    }
}

// -------------------- s = softmax(h @ linW + linb) over G=10 ------------------
__global__ __launch_bounds__(256) void softmax_kernel(
    const float* __restrict__ h, const float* __restrict__ linW,
    const float* __restrict__ linb, float* __restrict__ s)
{
    __shared__ float hs[64 * 132];
    __shared__ float lw[10 * 132];
    const int tid = threadIdx.x;
    const int nbase = blockIdx.x * 64;
    #pragma unroll
    for (int i = 0; i < 8; ++i) {
        int f = tid + i * 256;
        int row = f >> 5;
        int col = (f & 31) * 4;
        int n = nbase + row;
        float4 v = make_float4(0.f, 0.f, 0.f, 0.f);
        if (n < NN) v = *reinterpret_cast<const float4*>(h + (size_t)n * 128 + col);
        *reinterpret_cast<float4*>(hs + row * 132 + col) = v;
    }
    for (int idx = tid; idx < 1280; idx += 256) {
        int k = idx / 10, g = idx % 10;
        lw[g * 132 + k] = linW[idx];
    }
    __syncthreads();
    const int node = tid >> 2;
    const int part = tid & 3;
    float acc[10];
    #pragma unroll
    for (int g = 0; g < 10; ++g) acc[g] = 0.f;
    #pragma unroll
    for (int kk = 0; kk < 32; ++kk) {
        float hv = hs[node * 132 + part + 4 * kk];
        #pragma unroll
        for (int g = 0; g < 10; ++g) acc[g] += hv * lw[g * 132 + part + 4 * kk];
    }
    #pragma unroll
    for (int g = 0; g < 10; ++g) {
        acc[g] += __shfl_xor(acc[g], 1);
        acc[g] += __shfl_xor(acc[g], 2);
        acc[g] += linb[g];
    }
    int gn = nbase + node;
    if (gn < NN) {
        float m = acc[0];
        #pragma unroll
        for (int g = 1; g < 10; ++g) m = fmaxf(m, acc[g]);
        float sum = 0.f;
        float ex[10];
        #pragma unroll
        for (int g = 0; g < 10; ++g) { ex[g] = expf(acc[g] - m); sum += ex[g]; }
        float inv = 1.f / sum;
        #pragma unroll
        for (int q = 0; q < 3; ++q) {
            int gg = part + 4 * q;
            if (gg < 10) s[(size_t)gn * 10 + gg] = ex[gg] * inv;
        }
    }
}

// -------------------- batch stats ---------------------------------------------
__global__ __launch_bounds__(256) void stats_kernel(
    const float* __restrict__ h, const float* __restrict__ s,
    float* __restrict__ sum1, float* __restrict__ sum2)
{
    __shared__ float hs[64 * 128];
    __shared__ float ss[64 * 10];
    const int tid = threadIdx.x;
    const int c = tid & 127;
    const int g0 = (tid >> 7) * 5;
    float a1[5], a2[5];
    #pragma unroll
    for (int q = 0; q < 5; ++q) { a1[q] = 0.f; a2[q] = 0.f; }

    const int nchunks = (NN + 63) / 64;
    for (int chunk = blockIdx.x; chunk < nchunks; chunk += gridDim.x) {
        int nbase = chunk * 64;
        #pragma unroll
        for (int i = 0; i < 8; ++i) {
            int f = tid + i * 256;
            int row = f >> 5, col = (f & 31) * 4;
            int n = nbase + row;
            float4 v = make_float4(0.f, 0.f, 0.f, 0.f);
            if (n < NN) v = *reinterpret_cast<const float4*>(h + (size_t)n * 128 + col);
            *reinterpret_cast<float4*>(hs + row * 128 + col) = v;
        }
        for (int idx = tid; idx < 640; idx += 256) {
            int row = idx / 10, g = idx % 10;
            int n = nbase + row;
            ss[idx] = (n < NN) ? s[(size_t)n * 10 + g] : 0.f;
        }
        __syncthreads();
        int nmax = min(64, NN - nbase);
        for (int n = 0; n < nmax; ++n) {
            float hv = hs[n * 128 + c];
            #pragma unroll
            for (int q = 0; q < 5; ++q) {
                float p = ss[n * 10 + g0 + q] * hv;
                a1[q] += p;
                a2[q] += p * p;
            }
        }
        __syncthreads();
    }
    #pragma unroll
    for (int q = 0; q < 5; ++q) {
        atomicAdd(&sum1[(g0 + q) * 128 + c], a1[q]);
        atomicAdd(&sum2[(g0 + q) * 128 + c], a2[q]);
    }
}

// -------------------- finalize ------------------------------------------------
__global__ void finalize_kernel(
    const float* __restrict__ sum1, const float* __restrict__ sum2,
    const float* __restrict__ gamma, const float* __restrict__ beta,
    float* __restrict__ w, float* __restrict__ kvec)
{
    int c = threadIdx.x;   // 128 threads
    float kacc = 0.f;
    const float invn = 1.f / (float)NN;
    for (int g = 0; g < NG; ++g) {
        int idx = g * 128 + c;
        float mu = sum1[idx] * invn;
        float var = sum2[idx] * invn - mu * mu;
        float inv = rsqrtf(var + EPSV);
        float wg = inv * gamma[idx];
        w[idx] = wg;
        kacc += beta[idx] - mu * wg;
    }
    kvec[c] = kacc;
}

// -------------------- apply ----------------------------------------------------
template<bool LAST>
__global__ __launch_bounds__(256) void apply_kernel(
    const float* __restrict__ out, const float* __restrict__ h,
    const float* __restrict__ s, const float* __restrict__ w,
    const float* __restrict__ kvec, const float* __restrict__ initial,
    float* __restrict__ dst, short* __restrict__ outbf)
{
    __shared__ float ws_[1280];
    __shared__ float ks_[128];
    const int tid = threadIdx.x;
    for (int i = tid; i < 1280; i += 256) ws_[i] = w[i];
    if (tid < 128) ks_[tid] = kvec[tid];
    __syncthreads();
    const int c = tid & 127;
    const int half = tid >> 7;
    const int nbase = blockIdx.x * 64;
    for (int nn = 0; nn < 32; ++nn) {
        int n = nbase + nn * 2 + half;
        if (n >= NN) continue;
        float A = 0.f;
        #pragma unroll
        for (int g = 0; g < 10; ++g) A += s[(size_t)n * 10 + g] * ws_[g * 128 + c];
        float hv = h[(size_t)n * 128 + c];
        float ov = out[(size_t)n * 128 + c];
        float res = ov + hv + LAM * (hv * A + ks_[c]);
        if (LAST) res += initial[(size_t)n * 128 + c];
        dst[(size_t)n * 128 + c] = res;
        if (!LAST) outbf[(size_t)n * 128 + c] = (short)f2b(res);
    }
}

// ------------------------------------------------------------------------------
extern "C" void kernel_launch(void* const* d_in, const int* in_sizes, int n_in,
                              void* d_out, int out_size, void* d_ws, size_t ws_size,
                              hipStream_t stream)
{
    const float* x    = (const float*)d_in[0];
    const int*   eidx = (const int*)  d_in[1];
    const float* ef   = (const float*)d_in[2];
    const float* gf   = (const float*)d_in[3];
    const float* Wc   = (const float*)d_in[4];
    const float* bc   = (const float*)d_in[5];

    float* outb = (float*)d_out;
    float* p = (float*)d_ws;
    short* msgbf = (short*)p;          p += (size_t)NN * 64;   // NN*128 bf16
    short* outbf = (short*)p;          p += (size_t)NN * 64;   // NN*128 bf16
    float* initial = p;                p += (size_t)NN * 128;
    float* hbuf = p;                   p += (size_t)NN * 128;
    float* sbuf = p;                   p += (size_t)NN * 10;
    float* sum1 = p;                   p += 1280;
    float* sum2 = p;                   p += 1280;
    float* wbuf = p;                   p += 1280;
    float* kvec = p;                   p += 128;
    short* wct  = (short*)p;           // 40960 shorts
    short* wts  = wct + 40960;         // 4*16384 shorts

    // CSR scratch aliased into not-yet-written buffers
    int* cnt = (int*)initial;
    int* off = ((int*)initial) + NN;
    int* eid = (int*)hbuf;

    // weights -> bf16 transposed (independent of CSR chain)
    prep_kernel<<<416, 256, 0, stream>>>(
        Wc, (const float*)d_in[6], (const float*)d_in[8],
        (const float*)d_in[14], (const float*)d_in[16], wct, wts);

    // messages = segment_sum(edge_features, row), atomic-free gather
    hipMemsetAsync(cnt, 0, sizeof(int) * (size_t)NN, stream);
    hist_kernel<<<(NE + 255) / 256, 256, 0, stream>>>(eidx, cnt);
    scan_kernel<<<1, 1024, 0, stream>>>(cnt, off);
    fill_kernel<<<(NE + 255) / 256, 256, 0, stream>>>(eidx, cnt, eid);
    gather_kernel<<<(NN + 3) / 4, 256, 0, stream>>>(ef, off, eid, (unsigned*)msgbf);

    const int gblocks = (NN + 63) / 64;  // 782
    combine_mfma_kernel<<<gblocks, 256, 0, stream>>>(
        x, msgbf, gf, wct, bc, outb, initial, outbf);

    for (int b = 0; b < 2; ++b) {
        const float* b1    = (const float*)d_in[7 + 8 * b];
        const float* b2    = (const float*)d_in[9 + 8 * b];
        const float* linW  = (const float*)d_in[10 + 8 * b];
        const float* linb  = (const float*)d_in[11 + 8 * b];
        const float* gamma = (const float*)d_in[12 + 8 * b];
        const float* beta  = (const float*)d_in[13 + 8 * b];
        const short* w1t = wts + (size_t)(2 * b) * 16384;
        const short* w2t = wts + (size_t)(2 * b + 1) * 16384;

        fused12_kernel<<<gblocks, 256, 0, stream>>>(outbf, w1t, w2t, b1, b2, hbuf);
        softmax_kernel<<<gblocks, 256, 0, stream>>>(hbuf, linW, linb, sbuf);
        hipMemsetAsync(sum1, 0, sizeof(float) * 2560, stream);
        stats_kernel<<<256, 256, 0, stream>>>(hbuf, sbuf, sum1, sum2);
        finalize_kernel<<<1, 128, 0, stream>>>(sum1, sum2, gamma, beta, wbuf, kvec);
        if (b == 0)
            apply_kernel<false><<<gblocks, 256, 0, stream>>>(
                outb, hbuf, sbuf, wbuf, kvec, nullptr, outb, outbf);
        else
            apply_kernel<true><<<gblocks, 256, 0, stream>>>(
                outb, hbuf, sbuf, wbuf, kvec, initial, outb, nullptr);
    }
}

// Round 5
// 436.190 us; speedup vs baseline: 4.0621x; 1.3277x over previous
//
#include <hip/hip_runtime.h>
#include <math.h>

// Problem constants
constexpr int NN = 50000;      // nodes
constexpr int NE = 800000;     // edges
constexpr int HD = 128;        // hidden
constexpr int NG = 10;         // groups
constexpr float LAM = 0.01f;
constexpr float EPSV = 1e-5f;
constexpr int NBLK = (NN + 255) / 256;   // 196 scan blocks

typedef __attribute__((ext_vector_type(8))) short s8v;   // 8 bf16 (4 VGPRs)
typedef __attribute__((ext_vector_type(4))) float f4v;   // MFMA acc

__device__ __forceinline__ float softplus_f(float x) {
    return fmaxf(x, 0.f) + log1pf(expf(-fabsf(x)));
}
__device__ __forceinline__ unsigned short f2b(float f) {
    unsigned u = __float_as_uint(f);
    unsigned r = (u + 0x7FFFu + ((u >> 16) & 1u)) >> 16;
    return (unsigned short)r;
}
__device__ __forceinline__ float b2f(unsigned short u) {
    return __uint_as_float(((unsigned)u) << 16);
}

// -------------------- CSR build: histogram -------------------------------------
__global__ __launch_bounds__(256) void hist_kernel(
    const int* __restrict__ rows, int* __restrict__ cnt)
{
    int e = blockIdx.x * 256 + threadIdx.x;
    if (e < NE) atomicAdd(&cnt[rows[e]], 1);
}

// -------------------- scan stage 1: per-block sums (coalesced) ----------------
__global__ __launch_bounds__(256) void scan1_kernel(
    const int* __restrict__ cnt, int* __restrict__ bsum)
{
    __shared__ int red[256];
    int t = threadIdx.x;
    int i = blockIdx.x * 256 + t;
    red[t] = (i < NN) ? cnt[i] : 0;
    __syncthreads();
    for (int d = 128; d > 0; d >>= 1) {
        if (t < d) red[t] += red[t + d];
        __syncthreads();
    }
    if (t == 0) bsum[blockIdx.x] = red[0];
}

// -------------------- scan stage 2: exclusive scan of 196 partials ------------
__global__ __launch_bounds__(256) void scan2_kernel(
    const int* __restrict__ bsum, int* __restrict__ bbase)
{
    __shared__ int sh[256];
    int t = threadIdx.x;
    int v = (t < NBLK) ? bsum[t] : 0;
    sh[t] = v;
    __syncthreads();
    for (int d = 1; d < 256; d <<= 1) {
        int u = (t >= d) ? sh[t - d] : 0;
        __syncthreads();
        sh[t] += u;
        __syncthreads();
    }
    if (t < NBLK) bbase[t] = sh[t] - v;
}

// -------------------- scan stage 3: final offsets (coalesced) -----------------
__global__ __launch_bounds__(256) void scan3_kernel(
    const int* __restrict__ cnt, const int* __restrict__ bbase,
    int* __restrict__ off, int* __restrict__ cur)
{
    __shared__ int sh[256];
    int t = threadIdx.x;
    int i = blockIdx.x * 256 + t;
    int v = (i < NN) ? cnt[i] : 0;
    sh[t] = v;
    __syncthreads();
    for (int d = 1; d < 256; d <<= 1) {
        int u = (t >= d) ? sh[t - d] : 0;
        __syncthreads();
        sh[t] += u;
        __syncthreads();
    }
    int excl = sh[t] - v + bbase[blockIdx.x];
    if (i < NN) { off[i] = excl; cur[i] = excl; }
    if (i == NN - 1) off[NN] = NE;
}

// -------------------- CSR build: bucket fill ----------------------------------
__global__ __launch_bounds__(256) void fill_kernel(
    const int* __restrict__ rows, int* __restrict__ cur, int* __restrict__ eid)
{
    int e = blockIdx.x * 256 + threadIdx.x;
    if (e < NE) {
        int slot = atomicAdd(&cur[rows[e]], 1);
        eid[slot] = e;
    }
}

// -------------------- gather: msgbf[n] = bf16(sum of ef rows) ------------------
// one 64-lane wave per node; 32 lanes x float4 per edge, 2 edges in flight
__global__ __launch_bounds__(256) void gather_kernel(
    const float* __restrict__ ef, const int* __restrict__ off,
    const int* __restrict__ eid, uint2* __restrict__ msgbf)
{
    int node = blockIdx.x * 4 + (threadIdx.x >> 6);
    if (node >= NN) return;
    int lane = threadIdx.x & 63;
    int half = lane >> 5, lc = lane & 31;
    int b = off[node], e = off[node + 1];
    float4 acc = make_float4(0.f, 0.f, 0.f, 0.f);
    for (int i = b + half; i < e; i += 2) {
        int ed = eid[i];
        float4 v = *reinterpret_cast<const float4*>(ef + (size_t)ed * HD + lc * 4);
        acc.x += v.x; acc.y += v.y; acc.z += v.z; acc.w += v.w;
    }
    acc.x += __shfl_xor(acc.x, 32);
    acc.y += __shfl_xor(acc.y, 32);
    acc.z += __shfl_xor(acc.z, 32);
    acc.w += __shfl_xor(acc.w, 32);
    if (half == 0) {
        uint2 pk;
        pk.x = (unsigned)f2b(acc.x) | ((unsigned)f2b(acc.y) << 16);
        pk.y = (unsigned)f2b(acc.z) | ((unsigned)f2b(acc.w) << 16);
        // 128 bf16 per node = 32 uint2; lane lc owns bf16 cols 4*lc..4*lc+3
        msgbf[(size_t)node * 32 + lc] = pk;
    }
}

// -------------------- prep: weights -> bf16, transposed [n][k] -----------------
__global__ __launch_bounds__(256) void prep_kernel(
    const float* __restrict__ Wc,
    const float* __restrict__ W1a, const float* __restrict__ W2a,
    const float* __restrict__ W1b, const float* __restrict__ W2b,
    short* __restrict__ wct, short* __restrict__ wts)
{
    int i = blockIdx.x * 256 + threadIdx.x;
    if (i < 40960) {
        int n = i / 320, kk = i % 320;
        wct[i] = (short)f2b(Wc[kk * 128 + n]);
    } else if (i < 40960 + 4 * 16384) {
        int j = i - 40960;
        int mat = j >> 14;
        int idx = j & 16383;
        int n = idx >> 7, kk = idx & 127;
        const float* src = (mat == 0) ? W1a : (mat == 1) ? W2a : (mat == 2) ? W1b : W2b;
        wts[j] = (short)f2b(src[kk * 128 + n]);
    }
}

// -------------------- combine: outbf = initbf = softplus([x|msg|g]@Wc + bc) ---
__global__ __launch_bounds__(256) void combine_mfma_kernel(
    const float* __restrict__ x, const short* __restrict__ msgbf,
    const float* __restrict__ gf, const short* __restrict__ wct,
    const float* __restrict__ bc,
    unsigned short* __restrict__ outbf, unsigned short* __restrict__ initbf)
{
    __shared__ short As[64 * 72];
    __shared__ short Ws[128 * 72];
    __shared__ float bcs[128];
    const int tid = threadIdx.x;
    const int m0 = blockIdx.x * 64;
    if (tid < 128) bcs[tid] = bc[tid];
    const int lane = tid & 63;
    const int wv = tid >> 6;
    const int fr = lane & 15;
    const int fc = lane >> 4;

    f4v acc[8];
    #pragma unroll
    for (int ct = 0; ct < 8; ++ct) acc[ct] = (f4v){0.f, 0.f, 0.f, 0.f};

    const int arow = tid >> 2;
    const int aseg = (tid & 3) * 16;
    const int wcol = tid >> 1;
    const int wseg = (tid & 1) * 32;

    for (int c = 0; c < 5; ++c) {
        const int k0 = c * 64;
        {
            short tmp[16];
            int grow = m0 + arow;
            if (grow >= NN) {
                #pragma unroll
                for (int j = 0; j < 16; ++j) tmp[j] = 0;
            } else if (c < 2) {
                const float* src = x + (size_t)grow * 128 + k0 + aseg;
                #pragma unroll
                for (int q = 0; q < 4; ++q) {
                    float4 v = *reinterpret_cast<const float4*>(src + 4 * q);
                    tmp[4*q+0] = (short)f2b(v.x); tmp[4*q+1] = (short)f2b(v.y);
                    tmp[4*q+2] = (short)f2b(v.z); tmp[4*q+3] = (short)f2b(v.w);
                }
            } else if (c < 4) {
                const short* src = msgbf + (size_t)grow * 128 + (k0 - 128) + aseg;
                *(s8v*)tmp = *(const s8v*)src;
                *(s8v*)(tmp + 8) = *(const s8v*)(src + 8);
            } else {
                const float* src = gf + aseg;
                #pragma unroll
                for (int q = 0; q < 4; ++q) {
                    float4 v = *reinterpret_cast<const float4*>(src + 4 * q);
                    tmp[4*q+0] = (short)f2b(v.x); tmp[4*q+1] = (short)f2b(v.y);
                    tmp[4*q+2] = (short)f2b(v.z); tmp[4*q+3] = (short)f2b(v.w);
                }
            }
            *(s8v*)&As[arow * 72 + aseg] = *(s8v*)tmp;
            *(s8v*)&As[arow * 72 + aseg + 8] = *(s8v*)(tmp + 8);
        }
        {
            const short* src = wct + (size_t)wcol * 320 + k0 + wseg;
            #pragma unroll
            for (int j = 0; j < 4; ++j)
                *(s8v*)&Ws[wcol * 72 + wseg + 8 * j] = *(const s8v*)(src + 8 * j);
        }
        __syncthreads();
        const short* ap = As + (wv * 16 + fr) * 72 + fc * 8;
        const short* bp = Ws + fr * 72 + fc * 8;
        #pragma unroll
        for (int ks = 0; ks < 2; ++ks) {
            s8v a = *(const s8v*)(ap + ks * 32);
            #pragma unroll
            for (int ct = 0; ct < 8; ++ct) {
                s8v b = *(const s8v*)(bp + ct * 16 * 72 + ks * 32);
                acc[ct] = __builtin_amdgcn_mfma_f32_16x16x32_bf16(a, b, acc[ct], 0, 0, 0);
            }
        }
        __syncthreads();
    }
    const int rbase = m0 + wv * 16 + fc * 4;
    #pragma unroll
    for (int ct = 0; ct < 8; ++ct) {
        int col = ct * 16 + fr;
        float bv = bcs[col];
        #pragma unroll
        for (int r = 0; r < 4; ++r) {
            int row = rbase + r;
            if (row < NN) {
                unsigned short b = f2b(softplus_f(acc[ct][r] + bv));
                outbf[(size_t)row * 128 + col] = b;
                initbf[(size_t)row * 128 + col] = b;
            }
        }
    }
}

// ---- fused12: h = softplus(out@W1+b1)@W2 + b2 ; s = softmax(h@linW+linb) -----
__global__ __launch_bounds__(256) void fused12_kernel(
    const unsigned short* __restrict__ outbf, const short* __restrict__ w1t,
    const short* __restrict__ w2t, const float* __restrict__ b1,
    const float* __restrict__ b2, const float* __restrict__ linW,
    const float* __restrict__ linb,
    unsigned short* __restrict__ hbf, float* __restrict__ sout)
{
    __shared__ short As[64 * 136];
    __shared__ short Ws[128 * 136];
    __shared__ short Ts[64 * 136];
    __shared__ float b1s[128], b2s[128];
    __shared__ float lws[128 * 11];
    __shared__ float lbs[10];
    const int tid = threadIdx.x;
    const int m0 = blockIdx.x * 64;
    if (tid < 128) { b1s[tid] = b1[tid]; b2s[tid] = b2[tid]; }
    for (int i = tid; i < 1280; i += 256) lws[(i / 10) * 11 + (i % 10)] = linW[i];
    if (tid < 10) lbs[tid] = linb[tid];
    const int lane = tid & 63;
    const int wv = tid >> 6;
    const int fr = lane & 15;
    const int fc = lane >> 4;

    // stage A (running out, bf16)
    {
        int row = tid >> 2, seg = (tid & 3) * 32;
        int grow = m0 + row;
        s8v v[4];
        if (grow < NN) {
            const short* src = (const short*)outbf + (size_t)grow * 128 + seg;
            #pragma unroll
            for (int j = 0; j < 4; ++j) v[j] = *(const s8v*)(src + 8 * j);
        } else {
            s8v z = {0,0,0,0,0,0,0,0};
            #pragma unroll
            for (int j = 0; j < 4; ++j) v[j] = z;
        }
        #pragma unroll
        for (int j = 0; j < 4; ++j) *(s8v*)&As[row * 136 + seg + 8 * j] = v[j];
    }
    // stage W1t
    {
        int col = tid >> 1, seg = (tid & 1) * 64;
        const short* src = w1t + (size_t)col * 128 + seg;
        #pragma unroll
        for (int j = 0; j < 8; ++j)
            *(s8v*)&Ws[col * 136 + seg + 8 * j] = *(const s8v*)(src + 8 * j);
    }
    __syncthreads();

    f4v acc[8];
    #pragma unroll
    for (int ct = 0; ct < 8; ++ct) acc[ct] = (f4v){0.f, 0.f, 0.f, 0.f};
    {
        const short* ap = As + (wv * 16 + fr) * 136 + fc * 8;
        const short* bp = Ws + fr * 136 + fc * 8;
        #pragma unroll
        for (int ks = 0; ks < 4; ++ks) {
            s8v a = *(const s8v*)(ap + ks * 32);
            #pragma unroll
            for (int ct = 0; ct < 8; ++ct) {
                s8v b = *(const s8v*)(bp + ct * 16 * 136 + ks * 32);
                acc[ct] = __builtin_amdgcn_mfma_f32_16x16x32_bf16(a, b, acc[ct], 0, 0, 0);
            }
        }
    }
    // t = softplus(.+b1) -> Ts bf16
    {
        int rb = wv * 16 + fc * 4;
        #pragma unroll
        for (int ct = 0; ct < 8; ++ct) {
            int col = ct * 16 + fr;
            float bv = b1s[col];
            #pragma unroll
            for (int r = 0; r < 4; ++r)
                Ts[(rb + r) * 136 + col] = (short)f2b(softplus_f(acc[ct][r] + bv));
        }
    }
    __syncthreads();
    // stage W2t over Ws
    {
        int col = tid >> 1, seg = (tid & 1) * 64;
        const short* src = w2t + (size_t)col * 128 + seg;
        #pragma unroll
        for (int j = 0; j < 8; ++j)
            *(s8v*)&Ws[col * 136 + seg + 8 * j] = *(const s8v*)(src + 8 * j);
    }
    __syncthreads();

    #pragma unroll
    for (int ct = 0; ct < 8; ++ct) acc[ct] = (f4v){0.f, 0.f, 0.f, 0.f};
    {
        const short* ap = Ts + (wv * 16 + fr) * 136 + fc * 8;
        const short* bp = Ws + fr * 136 + fc * 8;
        #pragma unroll
        for (int ks = 0; ks < 4; ++ks) {
            s8v a = *(const s8v*)(ap + ks * 32);
            #pragma unroll
            for (int ct = 0; ct < 8; ++ct) {
                s8v b = *(const s8v*)(bp + ct * 16 * 136 + ks * 32);
                acc[ct] = __builtin_amdgcn_mfma_f32_16x16x32_bf16(a, b, acc[ct], 0, 0, 0);
            }
        }
    }
    // h = acc + b2 (keep in acc)
    #pragma unroll
    for (int ct = 0; ct < 8; ++ct) {
        float bv = b2s[ct * 16 + fr];
        #pragma unroll
        for (int r = 0; r < 4; ++r) acc[ct][r] += bv;
    }
    // dots[r][g] = partial h@linW over this lane's 8 cols
    float dot[4][10];
    #pragma unroll
    for (int r = 0; r < 4; ++r)
        #pragma unroll
        for (int g = 0; g < 10; ++g) dot[r][g] = 0.f;
    #pragma unroll
    for (int ct = 0; ct < 8; ++ct) {
        #pragma unroll
        for (int g = 0; g < 10; ++g) {
            float lwv = lws[(ct * 16 + fr) * 11 + g];
            #pragma unroll
            for (int r = 0; r < 4; ++r) dot[r][g] += acc[ct][r] * lwv;
        }
    }
    // reduce over the 16 fr lanes (butterfly leaves result in all lanes)
    #pragma unroll
    for (int r = 0; r < 4; ++r)
        #pragma unroll
        for (int g = 0; g < 10; ++g) {
            float v = dot[r][g];
            v += __shfl_xor(v, 1);
            v += __shfl_xor(v, 2);
            v += __shfl_xor(v, 4);
            v += __shfl_xor(v, 8);
            dot[r][g] = v + lbs[g];
        }
    // softmax per row
    #pragma unroll
    for (int r = 0; r < 4; ++r) {
        float m = dot[r][0];
        #pragma unroll
        for (int g = 1; g < 10; ++g) m = fmaxf(m, dot[r][g]);
        float sum = 0.f;
        #pragma unroll
        for (int g = 0; g < 10; ++g) { dot[r][g] = expf(dot[r][g] - m); sum += dot[r][g]; }
        float inv = 1.f / sum;
        #pragma unroll
        for (int g = 0; g < 10; ++g) dot[r][g] *= inv;
    }
    const int growb = m0 + wv * 16 + fc * 4;
    // write h (bf16)
    #pragma unroll
    for (int ct = 0; ct < 8; ++ct) {
        int col = ct * 16 + fr;
        #pragma unroll
        for (int r = 0; r < 4; ++r) {
            int row = growb + r;
            if (row < NN) hbf[(size_t)row * 128 + col] = f2b(acc[ct][r]);
        }
    }
    // write s: lane fr writes group fr
    if (fr < 10) {
        #pragma unroll
        for (int r = 0; r < 4; ++r) {
            int row = growb + r;
            if (row < NN) {
                float v = 0.f;
                #pragma unroll
                for (int g = 0; g < 10; ++g) v = (fr == g) ? dot[r][g] : v;
                sout[(size_t)row * 10 + fr] = v;
            }
        }
    }
}

// -------------------- batch stats ---------------------------------------------
__global__ __launch_bounds__(256) void stats_kernel(
    const unsigned short* __restrict__ hbf, const float* __restrict__ s,
    float* __restrict__ sum1, float* __restrict__ sum2)
{
    __shared__ float hs[64 * 128];
    __shared__ float ss[640];
    const int tid = threadIdx.x;
    const int c = tid & 127;
    const int g0 = (tid >> 7) * 5;
    float a1[5], a2[5];
    #pragma unroll
    for (int q = 0; q < 5; ++q) { a1[q] = 0.f; a2[q] = 0.f; }

    const int nchunks = (NN + 63) / 64;
    for (int chunk = blockIdx.x; chunk < nchunks; chunk += gridDim.x) {
        int nbase = chunk * 64;
        #pragma unroll
        for (int i = 0; i < 4; ++i) {
            int f = tid + i * 256;          // 1024 x ushort8
            int row = f >> 4, col = (f & 15) * 8;
            int n = nbase + row;
            if (n < NN) {
                s8v raw = *(const s8v*)((const short*)hbf + (size_t)n * 128 + col);
                #pragma unroll
                for (int j = 0; j < 8; ++j)
                    hs[row * 128 + col + j] = b2f((unsigned short)raw[j]);
            } else {
                #pragma unroll
                for (int j = 0; j < 8; ++j) hs[row * 128 + col + j] = 0.f;
            }
        }
        for (int idx = tid; idx < 640; idx += 256) {
            int n = nbase + idx / 10;
            ss[idx] = (n < NN) ? s[(size_t)n * 10 + idx % 10] : 0.f;
        }
        __syncthreads();
        int nmax = min(64, NN - nbase);
        for (int n = 0; n < nmax; ++n) {
            float hv = hs[n * 128 + c];
            #pragma unroll
            for (int q = 0; q < 5; ++q) {
                float p = ss[n * 10 + g0 + q] * hv;
                a1[q] += p;
                a2[q] += p * p;
            }
        }
        __syncthreads();
    }
    #pragma unroll
    for (int q = 0; q < 5; ++q) {
        atomicAdd(&sum1[(g0 + q) * 128 + c], a1[q]);
        atomicAdd(&sum2[(g0 + q) * 128 + c], a2[q]);
    }
}

// -------------------- finalize ------------------------------------------------
__global__ void finalize_kernel(
    const float* __restrict__ sum1, const float* __restrict__ sum2,
    const float* __restrict__ gamma, const float* __restrict__ beta,
    float* __restrict__ w, float* __restrict__ kvec)
{
    int c = threadIdx.x;   // 128 threads
    float kacc = 0.f;
    const float invn = 1.f / (float)NN;
    for (int g = 0; g < NG; ++g) {
        int idx = g * 128 + c;
        float mu = sum1[idx] * invn;
        float var = sum2[idx] * invn - mu * mu;
        float inv = rsqrtf(var + EPSV);
        float wg = inv * gamma[idx];
        w[idx] = wg;
        kacc += beta[idx] - mu * wg;
    }
    kvec[c] = kacc;
}

// -------------------- apply ----------------------------------------------------
template<bool LAST>
__global__ __launch_bounds__(256) void apply_kernel(
    const unsigned short* __restrict__ outbf_in,
    const unsigned short* __restrict__ hbf,
    const float* __restrict__ s, const float* __restrict__ w,
    const float* __restrict__ kvec, const unsigned short* __restrict__ initbf,
    float* __restrict__ dstf, unsigned short* __restrict__ outbf_out)
{
    __shared__ __align__(16) float ws_[1280];
    __shared__ float ks_[128];
    __shared__ float ss_[640];
    const int tid = threadIdx.x;
    const int m0 = blockIdx.x * 64;
    for (int i = tid; i < 320; i += 256)
        ((float4*)ws_)[i] = ((const float4*)w)[i];
    if (tid < 128) ks_[tid] = kvec[tid];
    for (int i = tid; i < 640; i += 256) {
        int n = m0 + i / 10;
        ss_[i] = (n < NN) ? s[(size_t)n * 10 + i % 10] : 0.f;
    }
    __syncthreads();
    const int tc = tid & 31, rg = tid >> 5;
    #pragma unroll
    for (int p = 0; p < 8; ++p) {
        int nl = p * 8 + rg;
        int n = m0 + nl;
        if (n >= NN) continue;
        float A0 = 0.f, A1 = 0.f, A2 = 0.f, A3 = 0.f;
        #pragma unroll
        for (int g = 0; g < 10; ++g) {
            float sv = ss_[nl * 10 + g];
            float4 wv = *reinterpret_cast<const float4*>(&ws_[g * 128 + tc * 4]);
            A0 += sv * wv.x; A1 += sv * wv.y; A2 += sv * wv.z; A3 += sv * wv.w;
        }
        ushort4 hv4 = *reinterpret_cast<const ushort4*>(hbf + (size_t)n * 128 + tc * 4);
        ushort4 ov4 = *reinterpret_cast<const ushort4*>(outbf_in + (size_t)n * 128 + tc * 4);
        float h0 = b2f(hv4.x), h1 = b2f(hv4.y), h2 = b2f(hv4.z), h3 = b2f(hv4.w);
        float r0 = b2f(ov4.x) + h0 + LAM * (h0 * A0 + ks_[tc * 4 + 0]);
        float r1 = b2f(ov4.y) + h1 + LAM * (h1 * A1 + ks_[tc * 4 + 1]);
        float r2 = b2f(ov4.z) + h2 + LAM * (h2 * A2 + ks_[tc * 4 + 2]);
        float r3 = b2f(ov4.w) + h3 + LAM * (h3 * A3 + ks_[tc * 4 + 3]);
        if (LAST) {
            ushort4 iv4 = *reinterpret_cast<const ushort4*>(initbf + (size_t)n * 128 + tc * 4);
            r0 += b2f(iv4.x); r1 += b2f(iv4.y); r2 += b2f(iv4.z); r3 += b2f(iv4.w);
            float4 o = make_float4(r0, r1, r2, r3);
            *reinterpret_cast<float4*>(dstf + (size_t)n * 128 + tc * 4) = o;
        } else {
            ushort4 o;
            o.x = f2b(r0); o.y = f2b(r1); o.z = f2b(r2); o.w = f2b(r3);
            *reinterpret_cast<ushort4*>(outbf_out + (size_t)n * 128 + tc * 4) = o;
        }
    }
}

// ------------------------------------------------------------------------------
extern "C" void kernel_launch(void* const* d_in, const int* in_sizes, int n_in,
                              void* d_out, int out_size, void* d_ws, size_t ws_size,
                              hipStream_t stream)
{
    const float* x    = (const float*)d_in[0];
    const int*   eidx = (const int*)  d_in[1];
    const float* ef   = (const float*)d_in[2];
    const float* gf   = (const float*)d_in[3];
    const float* Wc   = (const float*)d_in[4];
    const float* bc   = (const float*)d_in[5];

    float* p = (float*)d_ws;
    // zeroed region (single memset): [cnt NN ints][sum1a|sum2a|sum1b|sum2b]
    int*   cnt  = (int*)p;
    float* sums = p + NN;                                  // 4*1280 floats
    p += NN + 4 * 1280;
    unsigned short* msgbf  = (unsigned short*)p;  p += (size_t)NN * 64;
    unsigned short* outbf  = (unsigned short*)p;  p += (size_t)NN * 64;
    unsigned short* initbf = (unsigned short*)p;  p += (size_t)NN * 64;
    unsigned short* hbf    = (unsigned short*)p;  p += (size_t)NN * 64;
    float* sbuf = p;                              p += (size_t)NN * 10;
    float* wbuf = p;                              p += 1280;
    float* kvec = p;                              p += 128;
    short* wct  = (short*)p;                      // 40960 shorts
    short* wts  = wct + 40960;                    // 4*16384 shorts

    // CSR scratch aliased into buffers written later:
    int* off   = (int*)initbf;           // NN+1
    int* cur   = off + NN + 1;           // NN
    int* bsum  = cur + NN;               // NBLK
    int* bbase = bsum + NBLK;            // NBLK
    int* eid   = (int*)hbf;              // NE

    // weights -> bf16 transposed
    prep_kernel<<<416, 256, 0, stream>>>(
        Wc, (const float*)d_in[6], (const float*)d_in[8],
        (const float*)d_in[14], (const float*)d_in[16], wct, wts);

    // zero cnt + all stat sums in one memset
    hipMemsetAsync(cnt, 0, sizeof(int) * (NN + 4 * 1280), stream);

    // CSR build (coalesced hierarchical scan) + gather
    hist_kernel <<<(NE + 255) / 256, 256, 0, stream>>>(eidx, cnt);
    scan1_kernel<<<NBLK, 256, 0, stream>>>(cnt, bsum);
    scan2_kernel<<<1, 256, 0, stream>>>(bsum, bbase);
    scan3_kernel<<<NBLK, 256, 0, stream>>>(cnt, bbase, off, cur);
    fill_kernel <<<(NE + 255) / 256, 256, 0, stream>>>(eidx, cur, eid);
    gather_kernel<<<(NN + 3) / 4, 256, 0, stream>>>(ef, off, eid, (uint2*)msgbf);

    const int gblocks = (NN + 63) / 64;  // 782
    combine_mfma_kernel<<<gblocks, 256, 0, stream>>>(
        x, (const short*)msgbf, gf, wct, bc, outbf, initbf);

    for (int b = 0; b < 2; ++b) {
        const float* b1    = (const float*)d_in[7 + 8 * b];
        const float* b2    = (const float*)d_in[9 + 8 * b];
        const float* linW  = (const float*)d_in[10 + 8 * b];
        const float* linb  = (const float*)d_in[11 + 8 * b];
        const float* gamma = (const float*)d_in[12 + 8 * b];
        const float* beta  = (const float*)d_in[13 + 8 * b];
        const short* w1t = wts + (size_t)(2 * b) * 16384;
        const short* w2t = wts + (size_t)(2 * b + 1) * 16384;
        float* sum1 = sums + (size_t)b * 2560;
        float* sum2 = sum1 + 1280;

        fused12_kernel<<<gblocks, 256, 0, stream>>>(
            outbf, w1t, w2t, b1, b2, linW, linb, hbf, sbuf);
        stats_kernel<<<256, 256, 0, stream>>>(hbf, sbuf, sum1, sum2);
        finalize_kernel<<<1, 128, 0, stream>>>(sum1, sum2, gamma, beta, wbuf, kvec);
        if (b == 0)
            apply_kernel<false><<<gblocks, 256, 0, stream>>>(
                outbf, hbf, sbuf, wbuf, kvec, nullptr, nullptr, outbf);
        else
            apply_kernel<true><<<gblocks, 256, 0, stream>>>(
                outbf, hbf, sbuf, wbuf, kvec, initbf, (float*)d_out, nullptr);
    }
}